// Round 3
// baseline (6144.955 us; speedup 1.0000x reference)
//
#include <hip/hip_runtime.h>

#define TT 512
#define HH 256
#define EE 128
#define BB 256
#define CC 64
#define VV 50000
#define NTEAM 16
#define GSPLIT 8
#define NBLK (NTEAM * GSPLIT)  // 128

// workspace offsets (bytes), all 256-aligned
#define OFF_EMB   0ull           // 50000*128       = 6,400,000   (emb as fp8)
#define OFF_WFRAG 6400000ull     // 1024*384        =   393,216   (W fp8 frags, per-slice)
#define OFF_BIAS  6793216ull     // 1024*4          =     4,096   (b_ih+b_hh, gate-major)
#define OFF_WLIN  6797312ull     // 4*8*64*8*2      =    16,384   (W_lin bf16 frags)
#define OFF_LSTM  6813696ull     // 256*512*256*2   = 67,108,864  (lstm_out bf16)
#define OFF_LOG   73922560ull    // 256*512*64*4    = 33,554,432  (logits f32)
// overlaid on the logits region (used only during the scan, before logits exist):
#define OFF_HX    OFF_LOG                 // 2*16*16*256 = 131,072 (h exchange, fp8)
#define OFF_FLAG  (OFF_LOG + 131072ull)   // 512*16*8*4  = 262,144 (arrival flags)
#define WS_NEED   107476992ull

typedef __attribute__((ext_vector_type(4))) float    f32x4;
typedef __attribute__((ext_vector_type(4))) unsigned u32x4;
typedef __attribute__((ext_vector_type(2))) unsigned u32x2;
typedef __bf16 bf16x8_t __attribute__((ext_vector_type(8)));

__device__ __forceinline__ float rcp_f(float x) { return __builtin_amdgcn_rcpf(x); }
__device__ __forceinline__ unsigned short to_bf16(float f) {
  unsigned u = __float_as_uint(f);
  return (unsigned short)((u + 0x7fffu + ((u >> 16) & 1u)) >> 16);
}
__device__ __forceinline__ float sigm(float x) { return rcp_f(1.f + __expf(-x)); }
__device__ __forceinline__ float tanhf_(float x) { return 2.f * rcp_f(1.f + __expf(-2.f * x)) - 1.f; }
__device__ __forceinline__ f32x4 mfma8(long a, long b, f32x4 c) {
  return __builtin_amdgcn_mfma_f32_16x16x32_fp8_fp8(a, b, c, 0, 0, 0);
}

// ---------------- prep: emb fp32 -> fp8 e4m3 (unscaled) ----------------
__global__ void prep_emb(const float* __restrict__ emb, unsigned* __restrict__ out) {
  const int stride = gridDim.x * blockDim.x;
  for (int u = blockIdx.x * blockDim.x + threadIdx.x; u < (VV * EE / 4); u += stride) {
    const f32x4 f = ((const f32x4*)emb)[u];
    int r = __builtin_amdgcn_cvt_pk_fp8_f32(f[0], f[1], 0, false);
    r = __builtin_amdgcn_cvt_pk_fp8_f32(f[2], f[3], r, true);
    out[u] = (unsigned)r;
  }
}

// ------- prep: fp8 B-fragments for the team-split scan -------
// flat id = ((((g*8 + w)*12 + kk)*64) + l)*8 + j
// col16 = l&15 = hu_l*4 + gate ; hu = g*32 + w*4 + hu_l ; grow = gate*256 + hu
__global__ void prep_wfrag(const float* __restrict__ Wih, const float* __restrict__ Whh,
                           unsigned char* __restrict__ wf) {
  const int id = blockIdx.x * 256 + threadIdx.x;  // exactly 393216 threads
  const int j = id & 7, l = (id >> 3) & 63;
  const int t1 = id >> 9;
  const int kk = t1 % 12, t2 = t1 / 12;
  const int w = t2 & 7, g = t2 >> 3;
  const int gate = l & 3;
  const int hu = g * 32 + w * 4 + ((l >> 2) & 3);
  const int grow = gate * 256 + hu;
  const int k = kk * 32 + ((l >> 4) << 3) + j;
  const float v = (k < HH) ? 64.f * Whh[grow * HH + k] : 1024.f * Wih[grow * EE + (k - HH)];
  const int r = __builtin_amdgcn_cvt_pk_fp8_f32(v, 0.f, 0, false);
  wf[id] = (unsigned char)(r & 0xff);
}

__global__ void prep_bias(const float* __restrict__ bih, const float* __restrict__ bhh,
                          float* __restrict__ bp) {
  const int n = blockIdx.x * 256 + threadIdx.x;  // 1024 threads, gate-major already
  bp[n] = bih[n] + bhh[n];
}

__global__ void prep_wlin(const float* __restrict__ Wlin, unsigned short* __restrict__ wl) {
  const int id = blockIdx.x * 256 + threadIdx.x;  // 16384 threads
  const int j = id & 7, l = (id >> 3) & 63;
  const int kk = (id >> 9) & 7, q = id >> 12;
  const int c = q * 16 + (l & 15);
  const int k = kk * 32 + ((l >> 4) << 3) + j;
  wl[id] = to_bf16(Wlin[c * HH + k]);
}

__global__ void zero_flags(int* __restrict__ f) {
  f[blockIdx.x * 256 + threadIdx.x] = 0;  // 65536 ints
}

// ---------------- team-split persistent LSTM scan ----------------
// 128 blocks x 512 thr. Team s = bid&15 (16 seqs: b0=s*16); slice g = bid>>4
// owns gate-cols for h-units [g*32, g*32+32). Per wave: 16 cols = 4 hu x 4 gates.
// A = [16 seqs x 384 K] fp8 in MFMA-frag order, double-buffered.
// Per step: MFMA -> quad-transpose (lane gets i,f,g,o of ONE cell) -> activation
// (1 cell/thread) -> publish h slice to global hx + release flag -> poll team
// flags -> acquire fence -> rebuild A h-region. Teammates share bid%8 (same XCD).
__global__ __launch_bounds__(512, 2)
void lstm_scan(const int* __restrict__ sent, const unsigned char* __restrict__ emb8,
               const long* __restrict__ wfrag, const float* __restrict__ bias,
               unsigned short* __restrict__ lstm_out, unsigned char* __restrict__ hx,
               int* __restrict__ flags) {
  __shared__ __align__(16) unsigned char A_lds[2][6144];
  __shared__ int idx_lds[2][16];

  const int tid = threadIdx.x;
  const int lane = tid & 63;
  const int w = tid >> 6;           // wave 0..7
  const int s = blockIdx.x & 15;    // team
  const int g = blockIdx.x >> 4;    // gate-slice 0..7
  const int b0 = s * 16;

  // B-fragments (12 longs = whole slice share for this wave's 16 cols)
  long wb[12];
#pragma unroll
  for (int kk = 0; kk < 12; ++kk) wb[kk] = wfrag[((g * 8 + w) * 12 + kk) * 64 + lane];

  // this thread's cell: hu = g*32 + w*4 + ((lane>>2)&3), seq = (lane>>4)*4 + (lane&3)
  const int hu = g * 32 + w * 4 + ((lane >> 2) & 3);
  const int seq = ((lane >> 4) << 2) + (lane & 3);
  const float bi = bias[hu], bf = bias[256 + hu], bg = bias[512 + hu], bo = bias[768 + hu];

  ((long*)A_lds[0])[tid] = 0;  // zero h-region of buffer 0 (bytes 0..4095)
  if (tid < 16) {
    idx_lds[0][tid] = sent[(b0 + tid) * TT + 0];
    idx_lds[1][tid] = sent[(b0 + tid) * TT + 1];
  }
  __syncthreads();
  if (tid < 256) {  // gather x(0)
    const int sq = tid & 15, ch = tid >> 4;
    const int idx = idx_lds[0][sq];
    const u32x2 xr = *(const u32x2*)(emb8 + (size_t)idx * EE + ch * 8);
    *(u32x2*)(&A_lds[0][4096 + (ch >> 2) * 512 + (ch & 3) * 128 + sq * 8]) = xr;
  }
  __syncthreads();

  float cs = 0.f;
  const float S = 1.f / 1024.f;
  unsigned char* hx0 = hx + s * 4096;          // [seq][hu] fp8, x16 scale
  unsigned char* hx1 = hx + 65536 + s * 4096;
  const long outb = ((long)(b0 + seq) * TT) * HH + hu;

#pragma unroll 1
  for (int t = 0; t < TT; ++t) {
    const int p = (t + 1) & 1;
    if (tid < 16 && t + 2 < TT)
      idx_lds[t & 1][tid] = sent[(b0 + tid) * TT + t + 2];

    // gather emb fp8 row for t+1 (hidden under MFMA / exchange wait)
    u32x2 xr;
    const bool dog = (tid < 256) && (t + 1 < TT);
    if (dog) {
      const int idx = idx_lds[(t + 1) & 1][tid & 15];
      xr = *(const u32x2*)(emb8 + (size_t)idx * EE + ((tid >> 4) & 15) * 8);
    }

    // MFMA: two 6-deep chains
    const long* Ab = (const long*)(A_lds[t & 1]);
    f32x4 a0 = (f32x4){0.f, 0.f, 0.f, 0.f}, a1 = a0;
#pragma unroll
    for (int kk = 0; kk < 6; ++kk) a0 = mfma8(Ab[kk * 64 + lane], wb[kk], a0);
#pragma unroll
    for (int kk = 6; kk < 12; ++kk) a1 = mfma8(Ab[kk * 64 + lane], wb[kk], a1);

    if (dog)  // stash x(t+1) into next A buffer (region disjoint from current reads)
      *(u32x2*)(&A_lds[p][4096 + (((tid >> 4) & 15) >> 2) * 512 + (((tid >> 4) & 15) & 3) * 128 + (tid & 15) * 8]) = xr;

    float v0 = a0[0] + a1[0], v1 = a0[1] + a1[1], v2 = a0[2] + a1[2], v3 = a0[3] + a1[3];
    // 4x4 transpose within lane-quads: after this, lane (quad-offset j) holds
    // gates i,f,g,o (v0..v3) for seq-offset j.
    {
      const bool hi1 = lane & 1;
      float x01 = hi1 ? v0 : v1; x01 = __shfl_xor(x01, 1);
      if (hi1) v0 = x01; else v1 = x01;
      float x23 = hi1 ? v2 : v3; x23 = __shfl_xor(x23, 1);
      if (hi1) v2 = x23; else v3 = x23;
      const bool hi2 = lane & 2;
      float x02 = hi2 ? v0 : v2; x02 = __shfl_xor(x02, 2);
      if (hi2) v0 = x02; else v2 = x02;
      float x13 = hi2 ? v1 : v3; x13 = __shfl_xor(x13, 2);
      if (hi2) v1 = x13; else v3 = x13;
    }

    // LSTM cell (one (hu,seq) cell per thread)
    const float gi = v0 * S + bi;
    const float gf = v1 * S + bf;
    const float gg = v2 * S + bg;
    const float go = v3 * S + bo;
    cs = sigm(gf) * cs + sigm(gi) * tanhf_(gg);
    const float hv = sigm(go) * tanhf_(cs);

    // publish h (fp8 x16) + lstm_out (bf16)
    unsigned char* hxp = p ? hx1 : hx0;
    const int pk = __builtin_amdgcn_cvt_pk_fp8_f32(16.f * hv, 0.f, 0, false);
    hxp[seq * 256 + hu] = (unsigned char)(pk & 0xff);
    lstm_out[outb + (long)t * HH] = to_bf16(hv);

    __syncthreads();  // drains all global stores (vmcnt 0) before flag

    if (t + 1 < TT) {
      int* fl = flags + (t * 16 + s) * 8;
      if (tid == 0)
        __hip_atomic_store(fl + g, 1, __ATOMIC_RELEASE, __HIP_MEMORY_SCOPE_AGENT);
      // all waves poll team arrival
      for (;;) {
        int v = (lane < 8) ? __hip_atomic_load(fl + lane, __ATOMIC_RELAXED,
                                               __HIP_MEMORY_SCOPE_AGENT) : 1;
        if (__all(v != 0)) break;
        __builtin_amdgcn_s_sleep(1);
      }
      __builtin_amdgcn_fence(__ATOMIC_ACQUIRE, "agent");
      // rebuild A[p] h-region from the team exchange buffer (8B/thread)
      const int sq = tid & 15, h0 = (tid >> 4) * 8;
      const unsigned long long hw =
          *(const unsigned long long*)(hxp + sq * 256 + h0);
      *(unsigned long long*)(&A_lds[p][((h0 >> 5) << 9) + (((h0 & 31) >> 3) << 7) + sq * 8]) = hw;
      __syncthreads();  // h-region ready for step t+1
    }
  }
}

// ---------------- logits = lstm_out @ W_lin^T + b_lin ----------------
__global__ __launch_bounds__(256)
void logits_gemm(const unsigned short* __restrict__ lstm, const unsigned short* __restrict__ wl,
                 const float* __restrict__ blin, float* __restrict__ logits) {
  const int tid = threadIdx.x, l = tid & 63, wv = tid >> 6;
  const long m0 = (long)blockIdx.x * 64 + wv * 16;
  f32x4 ac[4];
#pragma unroll
  for (int q = 0; q < 4; ++q) ac[q] = (f32x4){0.f, 0.f, 0.f, 0.f};
  const unsigned short* arow = lstm + (m0 + (l & 15)) * HH + ((l >> 4) << 3);
#pragma unroll
  for (int kk = 0; kk < 8; ++kk) {
    const bf16x8_t a = __builtin_bit_cast(bf16x8_t, *(const u32x4*)(arow + kk * 32));
#pragma unroll
    for (int q = 0; q < 4; ++q) {
      const bf16x8_t b = __builtin_bit_cast(bf16x8_t, *(const u32x4*)(wl + (((q * 8 + kk) * 64 + l) << 3)));
      ac[q] = __builtin_amdgcn_mfma_f32_16x16x32_bf16(a, b, ac[q], 0, 0, 0);
    }
  }
  const int r0 = (l >> 4) << 2;
#pragma unroll
  for (int q = 0; q < 4; ++q) {
    const int col = q * 16 + (l & 15);
    const float bb = blin[col];
#pragma unroll
    for (int r = 0; r < 4; ++r)
      logits[(m0 + r0 + r) * CC + col] = ac[q][r] + bb;
  }
}

// ------------- log_softmax over time + product over time, per (b,c) -------------
// True product overflows fp32/fp64 (ref = +inf). Accumulate log2|logp| and emit
// exp2(min(sum,127)): exact when representable, finite otherwise (never inf/nan).
__global__ __launch_bounds__(256)
void softmax_prod(const float* __restrict__ logits, float* __restrict__ out) {
  __shared__ float lds[TT * CC];   // 128 KB
  __shared__ float red[3][4][CC];
  const int tid = threadIdx.x, b = blockIdx.x;
  const f32x4* src = (const f32x4*)(logits + (long)b * TT * CC);
  f32x4* dst = (f32x4*)lds;
#pragma unroll 1
  for (int i = tid; i < TT * CC / 4; i += 256) dst[i] = src[i];
  __syncthreads();

  const int c = tid & 63, part = tid >> 6;
  const int t0 = part * 128;
  float m = -3.0e38f;
  for (int k = 0; k < 128; ++k) m = fmaxf(m, lds[(t0 + k) * CC + c]);
  red[0][part][c] = m;
  __syncthreads();
  m = fmaxf(fmaxf(red[0][0][c], red[0][1][c]), fmaxf(red[0][2][c], red[0][3][c]));

  float ssum = 0.f;
  for (int k = 0; k < 128; ++k) ssum += __expf(lds[(t0 + k) * CC + c] - m);
  red[1][part][c] = ssum;
  __syncthreads();
  ssum = red[1][0][c] + red[1][1][c] + red[1][2][c] + red[1][3][c];
  const float lse = m + __logf(ssum);

  float pacc = 0.f;
  for (int k = 0; k < 128; ++k) pacc += __log2f(fabsf(lds[(t0 + k) * CC + c] - lse));
  red[2][part][c] = pacc;
  __syncthreads();
  if (part == 0) {
    const float tot = red[2][0][c] + red[2][1][c] + red[2][2][c] + red[2][3][c];
    out[b * CC + c] = exp2f(fminf(tot, 127.0f));
  }
}

extern "C" void kernel_launch(void* const* d_in, const int* in_sizes, int n_in,
                              void* d_out, int out_size, void* d_ws, size_t ws_size,
                              hipStream_t stream) {
  (void)in_sizes; (void)n_in; (void)out_size;
  if (ws_size < WS_NEED) return;  // produces 0-node graph -> explicit harness error

  const int*   sent = (const int*)d_in[0];
  const float* emb  = (const float*)d_in[1];
  const float* Wih  = (const float*)d_in[2];
  const float* Whh  = (const float*)d_in[3];
  const float* bih  = (const float*)d_in[4];
  const float* bhh  = (const float*)d_in[5];
  const float* Wlin = (const float*)d_in[6];
  const float* blin = (const float*)d_in[7];
  float* out = (float*)d_out;
  char* ws = (char*)d_ws;

  unsigned char*  emb8 = (unsigned char*)(ws + OFF_EMB);
  unsigned char*  wf   = (unsigned char*)(ws + OFF_WFRAG);
  float*          bp   = (float*)(ws + OFF_BIAS);
  unsigned short* wl   = (unsigned short*)(ws + OFF_WLIN);
  unsigned short* lo   = (unsigned short*)(ws + OFF_LSTM);
  float*          lg   = (float*)(ws + OFF_LOG);
  unsigned char*  hxb  = (unsigned char*)(ws + OFF_HX);
  int*            flg  = (int*)(ws + OFF_FLAG);

  prep_emb<<<1024, 256, 0, stream>>>(emb, (unsigned*)emb8);
  prep_wfrag<<<1536, 256, 0, stream>>>(Wih, Whh, wf);
  prep_bias<<<4, 256, 0, stream>>>(bih, bhh, bp);
  prep_wlin<<<64, 256, 0, stream>>>(Wlin, wl);
  zero_flags<<<256, 256, 0, stream>>>(flg);
  lstm_scan<<<NBLK, 512, 0, stream>>>(sent, emb8, (const long*)wf, bp, lo, hxb, flg);
  logits_gemm<<<2048, 256, 0, stream>>>(lo, wl, blin, lg);
  softmax_prod<<<256, 256, 0, stream>>>(lg, out);
}

// Round 4
// 1378.660 us; speedup vs baseline: 4.4572x; 4.4572x over previous
//
#include <hip/hip_runtime.h>

#define TT 512
#define HH 256
#define EE 128
#define BB 256
#define CC 64
#define VV 50000

// workspace offsets (bytes), all 256-aligned
#define OFF_EMB   0ull           // 50000*128       = 6,400,000   (emb as fp8)
#define OFF_WMX   6400000ull     // 16*4*2*64*32    =   262,144   (W_hh fp8 MX frags)
#define OFF_WX    6662144ull     // 16*4*4*64*8     =   131,072   (W_ih fp8 16x16x32 frags)
#define OFF_BIAS  6793216ull     // 1024*4          =     4,096   (b_ih+b_hh, permuted)
#define OFF_WLIN  6797312ull     // 4*8*64*8*2      =    16,384   (W_lin bf16 frags)
#define OFF_LSTM  6813696ull     // 256*512*256*2   = 67,108,864  (lstm_out bf16)
#define OFF_LOG   73922560ull    // 256*512*64*4    = 33,554,432  (logits f32)
#define WS_NEED   107476992ull

typedef __attribute__((ext_vector_type(4))) float    f32x4;
typedef __attribute__((ext_vector_type(4))) unsigned u32x4;
typedef __attribute__((ext_vector_type(2))) unsigned u32x2;
typedef __attribute__((ext_vector_type(8))) int      i32x8;
typedef __bf16 bf16x8_t __attribute__((ext_vector_type(8)));

__device__ __forceinline__ float rcp_f(float x) { return __builtin_amdgcn_rcpf(x); }
__device__ __forceinline__ unsigned short to_bf16(float f) {
  unsigned u = __float_as_uint(f);
  return (unsigned short)((u + 0x7fffu + ((u >> 16) & 1u)) >> 16);
}
__device__ __forceinline__ float sigm(float x) { return rcp_f(1.f + __expf(-x)); }
__device__ __forceinline__ float tanhf_(float x) { return 2.f * rcp_f(1.f + __expf(-2.f * x)) - 1.f; }
__device__ __forceinline__ f32x4 mfma8(long a, long b, f32x4 c) {
  return __builtin_amdgcn_mfma_f32_16x16x32_fp8_fp8(a, b, c, 0, 0, 0);
}
// MX-scaled fp8 GEMM, K=128, all scale exponents = 127 (x1.0) -> plain fp8 at 2x rate
__device__ __forceinline__ f32x4 mfma_mx(i32x8 a, i32x8 b, f32x4 c) {
  return __builtin_amdgcn_mfma_scale_f32_16x16x128_f8f6f4(
      a, b, c, 0, 0, 0, 0x7f7f7f7f, 0, 0x7f7f7f7f);
}

// ---------------- prep: emb fp32 -> fp8 e4m3 (unscaled) ----------------
__global__ void prep_emb(const float* __restrict__ emb, unsigned* __restrict__ out) {
  const int stride = gridDim.x * blockDim.x;
  for (int u = blockIdx.x * blockDim.x + threadIdx.x; u < (VV * EE / 4); u += stride) {
    const f32x4 f = ((const f32x4*)emb)[u];
    int r = __builtin_amdgcn_cvt_pk_fp8_f32(f[0], f[1], 0, false);
    r = __builtin_amdgcn_cvt_pk_fp8_f32(f[2], f[3], r, true);
    out[u] = (unsigned)r;
  }
}

// ------- prep: W_hh*64 -> fp8 MX B-fragments (16x16x128) -------
// flat id bits: w(4)|q(2)|T(1)|l(6)|b(5); k = T*128 + (l>>4)*32 + b
// col (l&15) of wave w, gate q -> original gate row g = q*256 + w*16 + (l&15)
__global__ void prep_wmx(const float* __restrict__ Whh, unsigned char* __restrict__ wf) {
  const int id = blockIdx.x * 256 + threadIdx.x;  // exactly 262144 threads
  const int b = id & 31, l = (id >> 5) & 63;
  const int T = (id >> 11) & 1, q = (id >> 12) & 3, w = id >> 14;
  const int grow = q * 256 + w * 16 + (l & 15);
  const int k = T * 128 + ((l >> 4) << 5) + b;
  const int r = __builtin_amdgcn_cvt_pk_fp8_f32(64.f * Whh[grow * HH + k], 0.f, 0, false);
  wf[id] = (unsigned char)(r & 0xff);
}

// ------- prep: W_ih*1024 -> fp8 16x16x32 B-fragments (4 K-tiles of 32) -------
// flat id bits: w(4)|q(2)|kk(2)|l(6)|j(3); e = kk*32 + (l>>4)*8 + j
__global__ void prep_wx(const float* __restrict__ Wih, unsigned char* __restrict__ wf) {
  const int id = blockIdx.x * 256 + threadIdx.x;  // exactly 131072 threads
  const int j = id & 7, l = (id >> 3) & 63;
  const int kk = (id >> 9) & 3, q = (id >> 11) & 3, w = id >> 13;
  const int grow = q * 256 + w * 16 + (l & 15);
  const int e = kk * 32 + ((l >> 4) << 3) + j;
  const int r = __builtin_amdgcn_cvt_pk_fp8_f32(1024.f * Wih[grow * EE + e], 0.f, 0, false);
  wf[id] = (unsigned char)(r & 0xff);
}

__global__ void prep_bias(const float* __restrict__ bih, const float* __restrict__ bhh,
                          float* __restrict__ bp) {
  const int n = blockIdx.x * 256 + threadIdx.x;  // 1024 threads
  const int w = n >> 6, q = (n >> 4) & 3, c = n & 15;
  const int g = q * 256 + w * 16 + c;
  bp[n] = bih[g] + bhh[g];
}

__global__ void prep_wlin(const float* __restrict__ Wlin, unsigned short* __restrict__ wl) {
  const int id = blockIdx.x * 256 + threadIdx.x;  // 16384 threads
  const int j = id & 7, l = (id >> 3) & 63;
  const int kk = (id >> 9) & 7, q = id >> 12;
  const int c = q * 16 + (l & 15);
  const int k = kk * 32 + ((l >> 4) << 3) + j;
  wl[id] = to_bf16(Wlin[c * HH + k]);
}

// ---------------- persistent LSTM scan: 16 blocks x 1024 thr, 16 seqs/block ----------------
// A buffer (double): bytes 0..4095 = h region in MX-fragment order:
//   byte(seq, k) at (k>>7)*2048 + ((k>>4)&1)*1024 + ((k>>5)&3)*256 + seq*16 + (k&15)
//   -> lane l reads 2x16B at {T*2048 + lane*16, +1024} : stride-16, conflict-free.
// bytes 4096..6143 = x region (16x16x32 frag order, as before):
//   byte(seq, kx) at 4096 + (kx>>5)*512 + ((kx>>3)&3)*128 + seq*8 + (kx&7)
// W_hh: MX frags in VGPRs (64). W_ih: kk0-1 in VGPRs, kk2-3 in LDS.
__global__ __launch_bounds__(1024)
void lstm_scan(const int* __restrict__ sent, const unsigned char* __restrict__ emb8,
               const i32x8* __restrict__ wmx, const long* __restrict__ wx,
               const float* __restrict__ bias, unsigned short* __restrict__ lstm_out) {
  __shared__ long wih_lds[8192];                          // 64 KB (W_ih kk2-3)
  __shared__ __align__(16) unsigned char A_lds[2][6144];  // 12 KB
  __shared__ int idx_lds[2][16];

  const int tid = threadIdx.x;
  const int lane = tid & 63;
  const int w = tid >> 6;
  const int b0 = blockIdx.x << 4;

  // W_hh MX fragments: [T][q], 8 VGPRs each = 64 VGPRs total
  i32x8 whh[2][4];
#pragma unroll
  for (int q = 0; q < 4; ++q)
#pragma unroll
    for (int T = 0; T < 2; ++T)
      whh[T][q] = wmx[((w * 4 + q) * 2 + T) * 64 + lane];

  // W_ih kk0-1 in regs (16 VGPRs)
  long wih2[4][2];
#pragma unroll
  for (int q = 0; q < 4; ++q)
#pragma unroll
    for (int kk = 0; kk < 2; ++kk)
      wih2[q][kk] = wx[((w * 4 + q) * 4 + kk) * 64 + lane];

  // W_ih kk2-3 to LDS
  for (int i = tid; i < 8192; i += 1024) {
    const int l = i & 63, r1 = i >> 6;
    const int kk2 = r1 & 1, q = (r1 >> 1) & 3, w2 = r1 >> 3;
    wih_lds[i] = wx[((w2 * 4 + q) * 4 + 2 + kk2) * 64 + l];
  }
  float bq[4];
#pragma unroll
  for (int q = 0; q < 4; ++q) bq[q] = bias[w * 64 + q * 16 + (lane & 15)];

  ((int*)A_lds)[tid] = 0;  // zero h-region of buffer 0 (bytes 0..4095)

  if (tid < 16) {
    idx_lds[0][tid] = sent[(b0 + tid) * TT + 0];
    idx_lds[1][tid] = sent[(b0 + tid) * TT + 1];
  }
  __syncthreads();

  if (tid < 256) {  // gather x(0)
    const int seq = tid & 15, ch = tid >> 4;
    const int idx = idx_lds[0][seq];
    const u32x2 xr = *(const u32x2*)(emb8 + (size_t)idx * EE + ch * 8);
    *(u32x2*)(&A_lds[0][4096 + (ch >> 2) * 512 + (ch & 3) * 128 + seq * 8]) = xr;
  }
  __syncthreads();

  float cs[4] = {0.f, 0.f, 0.f, 0.f};
  const int hc = w * 16 + (lane & 15);
  // h-region write base for this col (seq term added per store)
  const int hbase = ((hc >> 7) << 11) + (((hc >> 4) & 1) << 10) + (((hc >> 5) & 3) << 8) + (hc & 15);
  const int s0 = (lane >> 4) << 2;
  const long gb0 = ((long)(b0 + s0) * TT) * HH + hc;

#pragma unroll 1
  for (int t = 0; t < TT; ++t) {
    const int p = (t + 1) & 1;
    if (tid < 16 && t + 2 < TT)
      idx_lds[t & 1][tid] = sent[(b0 + tid) * TT + t + 2];

    // gather emb fp8 row for t+1 (latency hidden under MFMA)
    const int seq = tid & 15, ch = (tid >> 4) & 15;
    u32x2 xr;
    const bool dog = (tid < 256) && (t + 1 < TT);
    if (dog) {
      const int idx = idx_lds[(t + 1) & 1][seq];
      xr = *(const u32x2*)(emb8 + (size_t)idx * EE + ch * 8);
    }

    const unsigned char* Ah = A_lds[t & 1];
    const long* Ab = (const long*)(A_lds[t & 1]);
    f32x4 ac[4];
#pragma unroll
    for (int q = 0; q < 4; ++q) ac[q] = (f32x4){0.f, 0.f, 0.f, 0.f};

    // h-part: 2 MX tiles (K=128 each)
#pragma unroll
    for (int T = 0; T < 2; ++T) {
      const u32x4 alo = *(const u32x4*)(Ah + T * 2048 + lane * 16);
      const u32x4 ahi = *(const u32x4*)(Ah + T * 2048 + 1024 + lane * 16);
      i32x8 a;
      a[0] = alo[0]; a[1] = alo[1]; a[2] = alo[2]; a[3] = alo[3];
      a[4] = ahi[0]; a[5] = ahi[1]; a[6] = ahi[2]; a[7] = ahi[3];
#pragma unroll
      for (int q = 0; q < 4; ++q) ac[q] = mfma_mx(a, whh[T][q], ac[q]);
    }
    // x-part: 4 fp8 16x16x32 K-tiles; kk0-1 B from regs, kk2-3 B from LDS
#pragma unroll
    for (int kk = 0; kk < 2; ++kk) {
      const long a = Ab[(8 + kk) * 64 + lane];
#pragma unroll
      for (int q = 0; q < 4; ++q) ac[q] = mfma8(a, wih2[q][kk], ac[q]);
    }
#pragma unroll
    for (int kk = 0; kk < 2; ++kk) {
      const long a = Ab[(10 + kk) * 64 + lane];
#pragma unroll
      for (int q = 0; q < 4; ++q) {
        const long b = wih_lds[((w * 4 + q) * 2 + kk) * 64 + lane];
        ac[q] = mfma8(a, b, ac[q]);
      }
    }

    if (dog)  // stash x(t+1) into next A buffer (disjoint from current reads)
      *(u32x2*)(&A_lds[p][4096 + (ch >> 2) * 512 + (ch & 3) * 128 + seq * 8]) = xr;

    // elementwise LSTM cell (gate cols for this lane are all in ac[0..3][r])
    const float S = 1.f / 1024.f;
    float hv[4];
#pragma unroll
    for (int r = 0; r < 4; ++r) {
      const float gi = ac[0][r] * S + bq[0];
      const float gf = ac[1][r] * S + bq[1];
      const float gg = ac[2][r] * S + bq[2];
      const float go = ac[3][r] * S + bq[3];
      cs[r] = sigm(gf) * cs[r] + sigm(gi) * tanhf_(gg);
      hv[r] = sigm(go) * tanhf_(cs[r]);
    }

    // h(t+1): fp8 x16 into next A buffer (MX layout); bf16 to global lstm_out
    unsigned char* An = A_lds[p];
    const int p0 = __builtin_amdgcn_cvt_pk_fp8_f32(16.f * hv[0], 16.f * hv[1], 0, false);
    const int p1 = __builtin_amdgcn_cvt_pk_fp8_f32(16.f * hv[2], 16.f * hv[3], 0, false);
    An[hbase + (s0 + 0) * 16] = (unsigned char)(p0 & 0xff);
    An[hbase + (s0 + 1) * 16] = (unsigned char)((p0 >> 8) & 0xff);
    An[hbase + (s0 + 2) * 16] = (unsigned char)(p1 & 0xff);
    An[hbase + (s0 + 3) * 16] = (unsigned char)((p1 >> 8) & 0xff);

    const long gb = gb0 + (long)t * HH;
    lstm_out[gb]                     = to_bf16(hv[0]);
    lstm_out[gb + (long)TT * HH]     = to_bf16(hv[1]);
    lstm_out[gb + (long)2 * TT * HH] = to_bf16(hv[2]);
    lstm_out[gb + (long)3 * TT * HH] = to_bf16(hv[3]);

    __syncthreads();
  }
}

// ---------------- logits = lstm_out @ W_lin^T + b_lin ----------------
__global__ __launch_bounds__(256)
void logits_gemm(const unsigned short* __restrict__ lstm, const unsigned short* __restrict__ wl,
                 const float* __restrict__ blin, float* __restrict__ logits) {
  const int tid = threadIdx.x, l = tid & 63, wv = tid >> 6;
  const long m0 = (long)blockIdx.x * 64 + wv * 16;
  f32x4 ac[4];
#pragma unroll
  for (int q = 0; q < 4; ++q) ac[q] = (f32x4){0.f, 0.f, 0.f, 0.f};
  const unsigned short* arow = lstm + (m0 + (l & 15)) * HH + ((l >> 4) << 3);
#pragma unroll
  for (int kk = 0; kk < 8; ++kk) {
    const bf16x8_t a = __builtin_bit_cast(bf16x8_t, *(const u32x4*)(arow + kk * 32));
#pragma unroll
    for (int q = 0; q < 4; ++q) {
      const bf16x8_t b = __builtin_bit_cast(bf16x8_t, *(const u32x4*)(wl + (((q * 8 + kk) * 64 + l) << 3)));
      ac[q] = __builtin_amdgcn_mfma_f32_16x16x32_bf16(a, b, ac[q], 0, 0, 0);
    }
  }
  const int r0 = (l >> 4) << 2;
#pragma unroll
  for (int q = 0; q < 4; ++q) {
    const int col = q * 16 + (l & 15);
    const float bb = blin[col];
#pragma unroll
    for (int r = 0; r < 4; ++r)
      logits[(m0 + r0 + r) * CC + col] = ac[q][r] + bb;
  }
}

// ------------- log_softmax over time + product over time, per (b,c) -------------
// True product overflows fp32/fp64 (ref = +inf). Accumulate log2|logp| and emit
// exp2(min(sum,127)): exact when representable, finite otherwise (never inf/nan).
__global__ __launch_bounds__(256)
void softmax_prod(const float* __restrict__ logits, float* __restrict__ out) {
  __shared__ float lds[TT * CC];   // 128 KB
  __shared__ float red[3][4][CC];
  const int tid = threadIdx.x, b = blockIdx.x;
  const f32x4* src = (const f32x4*)(logits + (long)b * TT * CC);
  f32x4* dst = (f32x4*)lds;
#pragma unroll 1
  for (int i = tid; i < TT * CC / 4; i += 256) dst[i] = src[i];
  __syncthreads();

  const int c = tid & 63, part = tid >> 6;
  const int t0 = part * 128;
  float m = -3.0e38f;
  for (int k = 0; k < 128; ++k) m = fmaxf(m, lds[(t0 + k) * CC + c]);
  red[0][part][c] = m;
  __syncthreads();
  m = fmaxf(fmaxf(red[0][0][c], red[0][1][c]), fmaxf(red[0][2][c], red[0][3][c]));

  float ssum = 0.f;
  for (int k = 0; k < 128; ++k) ssum += __expf(lds[(t0 + k) * CC + c] - m);
  red[1][part][c] = ssum;
  __syncthreads();
  ssum = red[1][0][c] + red[1][1][c] + red[1][2][c] + red[1][3][c];
  const float lse = m + __logf(ssum);

  float pacc = 0.f;
  for (int k = 0; k < 128; ++k) pacc += __log2f(fabsf(lds[(t0 + k) * CC + c] - lse));
  red[2][part][c] = pacc;
  __syncthreads();
  if (part == 0) {
    const float tot = red[2][0][c] + red[2][1][c] + red[2][2][c] + red[2][3][c];
    out[b * CC + c] = exp2f(fminf(tot, 127.0f));
  }
}

extern "C" void kernel_launch(void* const* d_in, const int* in_sizes, int n_in,
                              void* d_out, int out_size, void* d_ws, size_t ws_size,
                              hipStream_t stream) {
  (void)in_sizes; (void)n_in; (void)out_size;
  if (ws_size < WS_NEED) return;  // produces 0-node graph -> explicit harness error

  const int*   sent = (const int*)d_in[0];
  const float* emb  = (const float*)d_in[1];
  const float* Wih  = (const float*)d_in[2];
  const float* Whh  = (const float*)d_in[3];
  const float* bih  = (const float*)d_in[4];
  const float* bhh  = (const float*)d_in[5];
  const float* Wlin = (const float*)d_in[6];
  const float* blin = (const float*)d_in[7];
  float* out = (float*)d_out;
  char* ws = (char*)d_ws;

  unsigned char*  emb8 = (unsigned char*)(ws + OFF_EMB);
  unsigned char*  wmx  = (unsigned char*)(ws + OFF_WMX);
  unsigned char*  wxp  = (unsigned char*)(ws + OFF_WX);
  float*          bp   = (float*)(ws + OFF_BIAS);
  unsigned short* wl   = (unsigned short*)(ws + OFF_WLIN);
  unsigned short* lo   = (unsigned short*)(ws + OFF_LSTM);
  float*          lg   = (float*)(ws + OFF_LOG);

  prep_emb<<<1024, 256, 0, stream>>>(emb, (unsigned*)emb8);
  prep_wmx<<<1024, 256, 0, stream>>>(Whh, wmx);
  prep_wx<<<512, 256, 0, stream>>>(Wih, wxp);
  prep_bias<<<4, 256, 0, stream>>>(bih, bhh, bp);
  prep_wlin<<<64, 256, 0, stream>>>(Wlin, wl);
  lstm_scan<<<16, 1024, 0, stream>>>(sent, emb8, (const i32x8*)wmx, (const long*)wxp, bp, lo);
  logits_gemm<<<2048, 256, 0, stream>>>(lo, wl, blin, lg);
  softmax_prod<<<256, 256, 0, stream>>>(lg, out);
}